// Round 12
// baseline (340.268 us; speedup 1.0000x reference)
//
#include <hip/hip_runtime.h>

// RISnetPIv2: B=128, U=16, A=1024, FEAT=4, INFO=8.
// Round-12: r11 (331.8us) + two structural cuts using r9-r11-verified MFMA
// machinery:
//  - layer_first -> MFMA: A K-split for fp32 input (lanes<32 [xh,xh] k0-7,
//    lanes>=32 [xr,xr] k8-15; B [Wh,Wr] both halves) = exact x*W1 in one
//    mfma; C = bias. Same single-wave pair-tiled structure as main.
//  - L7/L8 fusion: f7 ll is consumed only by L8 -> compute y.W8 in-register
//    at L7 (post-skip, fp32), shfl-combine halves, atomicAdd into outp[b,a];
//    L7 skips the 33.5MB ll store; L8 becomes a light finish kernel.

#define NB 128
#define NU 16
#define NA 1024

typedef float v2f __attribute__((ext_vector_type(2)));
typedef __attribute__((ext_vector_type(8))) short bf16x8;
typedef __attribute__((ext_vector_type(16))) float f32x16;

static constexpr float PI_F = 3.14159265358979323846f;

__device__ __forceinline__ unsigned int cvtpk(float a, float b) {
    unsigned int r;
    asm("v_cvt_pk_bf16_f32 %0, %1, %2" : "=v"(r) : "v"(a), "v"(b));
    return r;  // lo = bf16(a), hi = bf16(b), RNE
}
__device__ __forceinline__ float bf16hi(float x) {   // bf16(x) as fp32
    return __uint_as_float(cvtpk(x, x) << 16);
}
__device__ __forceinline__ void unpack8(uint4 v, float x[8]) {
    x[0] = __uint_as_float(v.x << 16); x[1] = __uint_as_float(v.x & 0xffff0000u);
    x[2] = __uint_as_float(v.y << 16); x[3] = __uint_as_float(v.y & 0xffff0000u);
    x[4] = __uint_as_float(v.z << 16); x[5] = __uint_as_float(v.z & 0xffff0000u);
    x[6] = __uint_as_float(v.w << 16); x[7] = __uint_as_float(v.w & 0xffff0000u);
}
__device__ __forceinline__ void store8f(unsigned short* p, const float y[8]) {
    uint4 v;
    v.x = cvtpk(y[0], y[1]); v.y = cvtpk(y[2], y[3]);
    v.z = cvtpk(y[4], y[5]); v.w = cvtpk(y[6], y[7]);
    *reinterpret_cast<uint4*>(p) = v;
}
__device__ __forceinline__ float treesum16(f32x16 v) {
    float a0 = v[0] + v[1], a1 = v[2] + v[3], a2 = v[4] + v[5], a3 = v[6] + v[7];
    float a4 = v[8] + v[9], a5 = v[10] + v[11], a6 = v[12] + v[13], a7 = v[14] + v[15];
    float b0 = a0 + a1, b1 = a2 + a3, b2 = a4 + a5, b3 = a6 + a7;
    return (b0 + b1) + (b2 + b3);
}

// ---------------- Layer 1: MFMA (input channel [B,4,U,A] fp32) ----------------
// Single-wave pair-tiled: wave = 32 antennas x 2 users/iter.
template <int NZ>
__global__ __launch_bounds__(64) void layer_first_t(
    const float* __restrict__ ch, const float* __restrict__ W1,
    const float* __restrict__ b1, unsigned short* __restrict__ ll_out,
    float* __restrict__ lg_out, float* __restrict__ gl_out,
    float* __restrict__ gg_out)
{
    constexpr int UN = NU / NZ;
    const int b = blockIdx.x;
    const int lane = threadIdx.x;
    const int o = lane & 31;
    const int h4 = 4 * (lane >> 5);
    const int half = lane >> 5;
    const int a32 = blockIdx.y * 32 + o;
    const int uz = blockIdx.z;
    const bool lohalf = lane < 32;

    __shared__ float s_lg[UN][8];
    __shared__ float s_gg[8];
    __shared__ float myl[8 * 68];
    for (int t = lane; t < UN * 8; t += 64) s_lg[t >> 3][t & 7] = 0.f;
    if (lane < 8) s_gg[lane] = 0.f;
    __syncthreads();

    const int jbr = o >> 3, oi = o & 7;

    // B: k0-3 = bf16(W1), k4-7 = residual (both lane-halves identical)
    bf16x8 Bfrag;
    {
        float wh[4], wr[4];
#pragma unroll
        for (int c = 0; c < 4; ++c) {
            float w = W1[(jbr * 4 + c) * 8 + oi];
            wh[c] = bf16hi(w);
            wr[c] = w - wh[c];
        }
        uint4 bw = make_uint4(cvtpk(wh[0], wh[1]), cvtpk(wh[2], wh[3]),
                              cvtpk(wr[0], wr[1]), cvtpk(wr[2], wr[3]));
        Bfrag = __builtin_bit_cast(bf16x8, bw);
    }
    // C = bias (same for every antenna row)
    f32x16 cT;
    {
        const float bb = b1[o];
#pragma unroll
        for (int r = 0; r < 16; ++r) cT[r] = bb;
    }

    f32x16 acc;
#pragma unroll
    for (int r = 0; r < 16; ++r) acc[r] = 0.f;

#pragma unroll
    for (int kp = 0; kp < UN / 2; ++kp) {
        const int u0 = uz * UN + 2 * kp;
        const int u_lane = u0 + half;

        float xc[4], xo[4];
#pragma unroll
        for (int c = 0; c < 4; ++c) {
            xc[c] = ch[(((size_t)b * 4 + c) * NU + u_lane) * NA + a32];
            xo[c] = __shfl_xor(xc[c], 32, 64);
        }
        float x0[4], x1[4];
#pragma unroll
        for (int c = 0; c < 4; ++c) {
            x0[c] = lohalf ? xc[c] : xo[c];   // user u0
            x1[c] = lohalf ? xo[c] : xc[c];   // user u0+1
        }
        // A: lanes<32 hold [xh,xh] (k0-7); lanes>=32 hold [xr,xr] (k8-15)
        bf16x8 A0, A1;
        {
            float v[4];
#pragma unroll
            for (int c = 0; c < 4; ++c) {
                float h = bf16hi(x0[c]);
                v[c] = lohalf ? h : (x0[c] - h);
            }
            unsigned t0 = cvtpk(v[0], v[1]), t1 = cvtpk(v[2], v[3]);
            uint4 u = make_uint4(t0, t1, t0, t1);
            A0 = __builtin_bit_cast(bf16x8, u);
#pragma unroll
            for (int c = 0; c < 4; ++c) {
                float h = bf16hi(x1[c]);
                v[c] = lohalf ? h : (x1[c] - h);
            }
            t0 = cvtpk(v[0], v[1]); t1 = cvtpk(v[2], v[3]);
            u = make_uint4(t0, t1, t0, t1);
            A1 = __builtin_bit_cast(bf16x8, u);
        }

        f32x16 d0 = __builtin_amdgcn_mfma_f32_32x32x16_bf16(A0, Bfrag, cT, 0, 0, 0);
        f32x16 d1 = __builtin_amdgcn_mfma_f32_32x32x16_bf16(A1, Bfrag, cT, 0, 0, 0);
#pragma unroll
        for (int r = 0; r < 16; ++r) {
            d0[r] = __builtin_fmaxf(d0[r], 0.f);
            d1[r] = __builtin_fmaxf(d1[r], 0.f);
        }

        float red0 = treesum16(d0);
        red0 += __shfl_xor(red0, 32, 64);
        if (lane >= 8 && lane < 16) atomicAdd(&s_lg[2 * kp][lane - 8], red0);
        float red1 = treesum16(d1);
        red1 += __shfl_xor(red1, 32, 64);
        if (lane >= 8 && lane < 16) atomicAdd(&s_lg[2 * kp + 1][lane - 8], red1);

#pragma unroll
        for (int r = 0; r < 16; ++r) acc[r] += d0[r] + d1[r];

        if (o < 8) {
#pragma unroll
            for (int q = 0; q < 4; ++q) {
                *reinterpret_cast<float4*>(&myl[o * 68 + q * 8 + h4]) =
                    make_float4(d0[4*q], d0[4*q+1], d0[4*q+2], d0[4*q+3]);
                *reinterpret_cast<float4*>(&myl[o * 68 + 32 + q * 8 + h4]) =
                    make_float4(d1[4*q], d1[4*q+1], d1[4*q+2], d1[4*q+3]);
            }
        }
        __syncthreads();
        float y[8];
#pragma unroll
        for (int c = 0; c < 8; ++c) y[c] = myl[c * 68 + lane];
        store8f(ll_out + (((size_t)(b * NU + u_lane)) * NA + a32) * 8, y);
        __syncthreads();
    }

    float gr = treesum16(acc);
    gr += __shfl_xor(gr, 32, 64);
    if (lane >= 24 && lane < 32) atomicAdd(&s_gg[lane - 24], gr);

    if (o >= 16 && o < 24) {
        const float invU = 1.f / 16.f;
        float* gp = gl_out + (((size_t)uz * NB + b) * 8 + (o - 16)) * NA
                  + blockIdx.y * 32;
#pragma unroll
        for (int q = 0; q < 4; ++q)
            *reinterpret_cast<float4*>(gp + q * 8 + h4) =
                make_float4(acc[4*q]*invU, acc[4*q+1]*invU, acc[4*q+2]*invU, acc[4*q+3]*invU);
    }
    __syncthreads();
    for (int t = lane; t < UN * 8; t += 64)
        atomicAdd(lg_out + ((size_t)b * NU + uz * UN + (t >> 3)) * 8 + (t & 7),
                  s_lg[t >> 3][t & 7]);
    if (lane < 8)
        atomicAdd(gg_out + b * 8 + lane, s_gg[lane]);
}

// -------- prep: base[b,u,32] = bias + lg·W_lg + gg·W_gg (unchanged) --------
__global__ __launch_bounds__(256) void prep_base_k(
    const float* __restrict__ lg_sum, const float* __restrict__ lg_skip,
    const float* __restrict__ gg_sum, const float* __restrict__ gg_skip,
    const float* __restrict__ Wl, const float* __restrict__ bl,
    float* __restrict__ base)
{
    const int t = blockIdx.x * 256 + threadIdx.x;  // b*16+u
    if (t >= NB * NU) return;
    const int b = t >> 4;
    const float invA = 1.f / 1024.f, invUA = 1.f / 16384.f;
    float lg[8], gg[8];
#pragma unroll
    for (int c = 0; c < 8; ++c) {
        float v = lg_sum[t * 8 + c] * invA;
        if (lg_skip) v = (v + lg_skip[t * 8 + c] * invA) * 0.5f;
        lg[c] = v;
    }
#pragma unroll
    for (int c = 0; c < 8; ++c) {
        float v = gg_sum[b * 8 + c] * invUA;
        if (gg_skip) v = (v + gg_skip[b * 8 + c] * invUA) * 0.5f;
        gg[c] = v;
    }
    float y[32];
#pragma unroll
    for (int o = 0; o < 32; ++o) y[o] = bl[o];
#pragma unroll
    for (int j = 0; j < 4; ++j)
#pragma unroll
        for (int c = 0; c < 8; ++c) {
            const float* wl = Wl + (j * 32 + 8 + c) * 8;
            const float* wg = Wl + (j * 32 + 24 + c) * 8;
#pragma unroll
            for (int oi = 0; oi < 8; ++oi) {
                y[j * 8 + oi] = fmaf(lg[c], wl[oi], y[j * 8 + oi]);
                y[j * 8 + oi] = fmaf(gg[c], wg[oi], y[j * 8 + oi]);
            }
        }
#pragma unroll
    for (int o = 0; o < 32; ++o) base[t * 32 + o] = y[o];
}

// ---------------- Layers 2..7: MFMA, single-wave, pair-tiled ----------------
// When W8v != nullptr (layer 7): skip the ll store; accumulate y·W8[0..7]
// into out_part[b,a] instead (f7 ll is consumed only by layer 8).
template <int NZ>
__global__ __launch_bounds__(64) void layer_main_t(
    const unsigned short* ll_in, const float* __restrict__ gl_in,
    const float* __restrict__ gl_skip, const float* __restrict__ base,
    const float* __restrict__ Wl,
    const unsigned short* __restrict__ ll_skip,          // layer 7: f3 ll
    const float* __restrict__ ch, const float* __restrict__ W1,
    const float* __restrict__ b1,                        // layer 5: recompute f1
    unsigned short* ll_out, float* __restrict__ lg_out,
    float* __restrict__ gl_out, float* __restrict__ gg_out,
    const float* __restrict__ W8v, float* __restrict__ out_part)
{
    constexpr int UN = NU / NZ;
    const int b = blockIdx.x;
    const int lane = threadIdx.x;       // 0..63
    const int o = lane & 31;
    const int h4 = 4 * (lane >> 5);
    const int half = lane >> 5;
    const int a32 = blockIdx.y * 32 + o;
    const int uz = blockIdx.z;
    const bool lohalf = lane < 32;

    __shared__ float s_lg[UN][8];
    __shared__ float s_gg[8];
    __shared__ float myl[8 * 68];
    for (int t = lane; t < UN * 8; t += 64) s_lg[t >> 3][t & 7] = 0.f;
    if (lane < 8) s_gg[lane] = 0.f;
    __syncthreads();

    const int jbr = o >> 3, oi = o & 7;

    // main B fragment: k0-7 = bf16(W_ll), k8-15 = residual (lane-half split)
    bf16x8 Bfrag;
    {
        unsigned int t4[4];
#pragma unroll
        for (int r = 0; r < 4; ++r) {
            float w0 = Wl[(jbr * 32 + 2 * r) * 8 + oi];
            float w1 = Wl[(jbr * 32 + 2 * r + 1) * 8 + oi];
            float h0 = bf16hi(w0), h1 = bf16hi(w1);
            t4[r] = cvtpk(lohalf ? w0 : (w0 - h0), lohalf ? w1 : (w1 - h1));
        }
        uint4 bw = make_uint4(t4[0], t4[1], t4[2], t4[3]);
        Bfrag = __builtin_bit_cast(bf16x8, bw);
    }

    // gl gather
    float g[8];
#pragma unroll
    for (int c = 0; c < 8; ++c) {
        float s = 0.f;
#pragma unroll
        for (int z = 0; z < NZ; ++z)
            s += gl_in[(((size_t)z * NB + b) * 8 + c) * NA + a32];
        g[c] = s;
    }
    if (gl_skip) {
#pragma unroll
        for (int c = 0; c < 8; ++c) {
            float s = 0.f;
#pragma unroll
            for (int z = 0; z < NZ; ++z)
                s += gl_skip[(((size_t)z * NB + b) * 8 + c) * NA + a32];
            g[c] = (g[c] + s) * 0.5f;
        }
    }

    // cT = g·W_gl via 2 MFMAs
    f32x16 cT;
    {
        bf16x8 Ag, Bh, Br;
        {
            unsigned int t4[4];
#pragma unroll
            for (int r = 0; r < 4; ++r) {
                float g0 = g[2 * r], g1 = g[2 * r + 1];
                float h0 = bf16hi(g0), h1 = bf16hi(g1);
                t4[r] = cvtpk(lohalf ? g0 : (g0 - h0), lohalf ? g1 : (g1 - h1));
            }
            uint4 u = make_uint4(t4[0], t4[1], t4[2], t4[3]);
            Ag = __builtin_bit_cast(bf16x8, u);
        }
        {
            unsigned int th[4], tr[4];
#pragma unroll
            for (int r = 0; r < 4; ++r) {
                float w0 = Wl[(jbr * 32 + 16 + 2 * r) * 8 + oi];
                float w1 = Wl[(jbr * 32 + 16 + 2 * r + 1) * 8 + oi];
                float h0 = bf16hi(w0), h1 = bf16hi(w1);
                th[r] = cvtpk(w0, w1);
                tr[r] = cvtpk(w0 - h0, w1 - h1);
            }
            uint4 uh = make_uint4(th[0], th[1], th[2], th[3]);
            uint4 ur = make_uint4(tr[0], tr[1], tr[2], tr[3]);
            Bh = __builtin_bit_cast(bf16x8, uh);
            Br = __builtin_bit_cast(bf16x8, ur);
        }
        f32x16 z16;
#pragma unroll
        for (int r = 0; r < 16; ++r) z16[r] = 0.f;
        cT = __builtin_amdgcn_mfma_f32_32x32x16_bf16(Ag, Bh, z16, 0, 0, 0);
        cT = __builtin_amdgcn_mfma_f32_32x32x16_bf16(Ag, Br, cT, 0, 0, 0);
    }

    f32x16 acc;
#pragma unroll
    for (int r = 0; r < 16; ++r) acc[r] = 0.f;
    float p8 = 0.f;

    const unsigned short* llrow =
        ll_in + (((size_t)(b * NU + uz * UN + half)) * NA + a32) * 8;
    const size_t pstride = (size_t)2 * NA * 8;
    uint4 xv = *reinterpret_cast<const uint4*>(llrow);

#pragma unroll
    for (int kp = 0; kp < UN / 2; ++kp) {
        const int u0 = uz * UN + 2 * kp;
        uint4 xnext = xv;
        if (kp + 1 < UN / 2)
            xnext = *reinterpret_cast<const uint4*>(llrow + (size_t)(kp + 1) * pstride);

        const float bse0 = base[(b * NU + u0) * 32 + o];
        const float bse1 = base[(b * NU + u0 + 1) * 32 + o];

        uint4 xs;
        xs.x = (unsigned)__shfl_xor((int)xv.x, 32, 64);
        xs.y = (unsigned)__shfl_xor((int)xv.y, 32, 64);
        xs.z = (unsigned)__shfl_xor((int)xv.z, 32, 64);
        xs.w = (unsigned)__shfl_xor((int)xv.w, 32, 64);
        uint4 a0u, a1u;
        a0u.x = lohalf ? xv.x : xs.x; a0u.y = lohalf ? xv.y : xs.y;
        a0u.z = lohalf ? xv.z : xs.z; a0u.w = lohalf ? xv.w : xs.w;
        a1u.x = lohalf ? xs.x : xv.x; a1u.y = lohalf ? xs.y : xv.y;
        a1u.z = lohalf ? xs.z : xv.z; a1u.w = lohalf ? xs.w : xv.w;
        bf16x8 A0 = __builtin_bit_cast(bf16x8, a0u);
        bf16x8 A1 = __builtin_bit_cast(bf16x8, a1u);

        f32x16 d0 = __builtin_amdgcn_mfma_f32_32x32x16_bf16(A0, Bfrag, cT, 0, 0, 0);
        f32x16 d1 = __builtin_amdgcn_mfma_f32_32x32x16_bf16(A1, Bfrag, cT, 0, 0, 0);
#pragma unroll
        for (int r = 0; r < 16; ++r) {
            d0[r] = __builtin_fmaxf(d0[r] + bse0, 0.f);
            d1[r] = __builtin_fmaxf(d1[r] + bse1, 0.f);
        }

        float red0 = treesum16(d0);
        red0 += __shfl_xor(red0, 32, 64);
        if (lane >= 8 && lane < 16) atomicAdd(&s_lg[2 * kp][lane - 8], red0);
        float red1 = treesum16(d1);
        red1 += __shfl_xor(red1, 32, 64);
        if (lane >= 8 && lane < 16) atomicAdd(&s_lg[2 * kp + 1][lane - 8], red1);

#pragma unroll
        for (int r = 0; r < 16; ++r) acc[r] += d0[r] + d1[r];

        if (o < 8) {
#pragma unroll
            for (int q = 0; q < 4; ++q) {
                *reinterpret_cast<float4*>(&myl[o * 68 + q * 8 + h4]) =
                    make_float4(d0[4*q], d0[4*q+1], d0[4*q+2], d0[4*q+3]);
                *reinterpret_cast<float4*>(&myl[o * 68 + 32 + q * 8 + h4]) =
                    make_float4(d1[4*q], d1[4*q+1], d1[4*q+2], d1[4*q+3]);
            }
        }
        __syncthreads();
        float y[8];
#pragma unroll
        for (int c = 0; c < 8; ++c) y[c] = myl[c * 68 + lane];

        const int u_lane = u0 + half;
        const size_t xoff = (((size_t)(b * NU + u_lane)) * NA + a32) * 8;
        if (ll_skip) {                       // layer 7: average with stored f3 ll
            float s[8];
            unpack8(*reinterpret_cast<const uint4*>(ll_skip + xoff), s);
#pragma unroll
            for (int c = 0; c < 8; ++c) y[c] = (y[c] + s[c]) * 0.5f;
        } else if (ch) {                     // layer 5: recompute f1 ll from input
            float xc[4];
#pragma unroll
            for (int c = 0; c < 4; ++c)
                xc[c] = ch[(((size_t)b * 4 + c) * NU + u_lane) * NA + a32];
            float s[8];
#pragma unroll
            for (int i = 0; i < 8; ++i) s[i] = b1[i];
#pragma unroll
            for (int c = 0; c < 4; ++c)
#pragma unroll
                for (int i = 0; i < 8; ++i)
                    s[i] = fmaf(xc[c], W1[c * 8 + i], s[i]);
#pragma unroll
            for (int i = 0; i < 8; ++i)
                y[i] = (y[i] + __builtin_fmaxf(s[i], 0.f)) * 0.5f;
        }
        if (W8v) {                           // layer 7: fused L8 ll-dot
            float d = 0.f;
#pragma unroll
            for (int c = 0; c < 8; ++c) d = fmaf(y[c], W8v[c], d);
            p8 += d;
        } else {
            store8f(ll_out + xoff, y);
        }
        __syncthreads();
        xv = xnext;
    }

    if (W8v) {
        p8 += __shfl_xor(p8, 32, 64);        // combine the two user-halves
        if (lohalf) atomicAdd(&out_part[(size_t)b * NA + a32], p8);
    }

    float gr = treesum16(acc);
    gr += __shfl_xor(gr, 32, 64);
    if (lane >= 24 && lane < 32) atomicAdd(&s_gg[lane - 24], gr);

    if (o >= 16 && o < 24) {
        const float invU = 1.f / 16.f;
        float* gp = gl_out + (((size_t)uz * NB + b) * 8 + (o - 16)) * NA
                  + blockIdx.y * 32;
#pragma unroll
        for (int q = 0; q < 4; ++q)
            *reinterpret_cast<float4*>(gp + q * 8 + h4) =
                make_float4(acc[4*q]*invU, acc[4*q+1]*invU, acc[4*q+2]*invU, acc[4*q+3]*invU);
    }
    __syncthreads();
    for (int t = lane; t < UN * 8; t += 64)
        atomicAdd(lg_out + ((size_t)b * NU + uz * UN + (t >> 3)) * 8 + (t & 7),
                  s_lg[t >> 3][t & 7]);
    if (lane < 8)
        atomicAdd(gg_out + b * 8 + lane, s_gg[lane]);
}

// ---------------- Layer 8 finish: out = pi*(outp/U + lg/gl/gg terms) --------
template <int NZ>
__global__ __launch_bounds__(128) void layer_out_fin(
    const float* __restrict__ outp,
    const float* __restrict__ lg7, const float* __restrict__ lg3,
    const float* __restrict__ gl7, const float* __restrict__ gl3,
    const float* __restrict__ gg7, const float* __restrict__ gg3,
    const float* __restrict__ W8, const float* __restrict__ b8,
    float* __restrict__ out)
{
    const int b = blockIdx.x;
    const int a = blockIdx.y * 128 + threadIdx.x;
    const float invA = 1.f / 1024.f, invUA = 1.f / 16384.f, invU = 1.f / 16.f;

    float acc = outp[(size_t)b * NA + a] * invU;

    float sb = b8[0];
#pragma unroll
    for (int c = 0; c < 8; ++c) {
        float s7 = 0.f, s3 = 0.f;
#pragma unroll
        for (int u = 0; u < NU; ++u) {
            s7 += lg7[(b * NU + u) * 8 + c];
            s3 += lg3[(b * NU + u) * 8 + c];
        }
        sb += ((s7 * invA + s3 * invA) * 0.5f * invU) * W8[8 + c];
    }
#pragma unroll
    for (int c = 0; c < 8; ++c)
        sb += ((gg7[b * 8 + c] + gg3[b * 8 + c]) * invUA * 0.5f) * W8[24 + c];

#pragma unroll
    for (int i = 0; i < 8; ++i) {
        float s7 = 0.f, s3 = 0.f;
#pragma unroll
        for (int z = 0; z < NZ; ++z) {
            s7 += gl7[(((size_t)z * NB + b) * 8 + i) * NA + a];
            s3 += gl3[(((size_t)z * NB + b) * 8 + i) * NA + a];
        }
        acc += 0.5f * (s7 + s3) * W8[16 + i];
    }
    out[(size_t)b * NA + a] = (acc + sb) * PI_F;
}

// ---------------- host ----------------
static constexpr size_t LLsz = (size_t)NB * NU * NA * 8;
static constexpr size_t GLsz = (size_t)NB * NA * 8;
static constexpr size_t LGsz = (size_t)NB * NU * 8;
static constexpr size_t GGsz = (size_t)NB * 8;

template <int NZ>
static void run_pipeline(const float* channel, const float* W1, const float* b1,
                         const float* Wm, const float* bm, const float* W8,
                         const float* b8, float* out, int out_bytes,
                         void* d_ws, hipStream_t stream)
{
    unsigned short* cur = (unsigned short*)d_ws;
    unsigned short* f3s = cur + LLsz;
    float* glb = (float*)(f3s + LLsz);
    float* g0 = glb;
    float* g1 = glb + (size_t)NZ * GLsz;
    float* g2 = glb + (size_t)2 * NZ * GLsz;
    float* g3 = glb + (size_t)3 * NZ * GLsz;
    float* lgb = glb + (size_t)4 * NZ * GLsz;
    float* ggb = lgb + 7 * LGsz;
    float* base = ggb + 7 * GGsz;
    float* outp = base + 2048 * 32;                 // [B,A] fused L8 partial

    hipMemsetAsync(lgb, 0, (7 * LGsz + 7 * GGsz) * sizeof(float), stream);
    hipMemsetAsync(outp, 0, (size_t)NB * NA * sizeof(float), stream);

    dim3 gridM(NB, NA / 32, NZ), blkM(64);
    dim3 gridO(NB, NA / 128), blkO(128);

    layer_first_t<NZ><<<gridM, blkM, 0, stream>>>(channel, W1, b1, cur, lgb, g0, ggb);

    prep_base_k<<<8, 256, 0, stream>>>(lgb, nullptr, ggb, nullptr, Wm, bm, base);
    layer_main_t<NZ><<<gridM, blkM, 0, stream>>>(cur, g0, nullptr, base, Wm,
        nullptr, nullptr, nullptr, nullptr,
        cur, lgb + 1 * LGsz, g2, ggb + 1 * GGsz, nullptr, nullptr);

    prep_base_k<<<8, 256, 0, stream>>>(lgb + 1 * LGsz, nullptr, ggb + 1 * GGsz, nullptr,
                                       Wm + 1024, bm + 32, base);
    layer_main_t<NZ><<<gridM, blkM, 0, stream>>>(cur, g2, nullptr, base, Wm + 1024,
        nullptr, nullptr, nullptr, nullptr,
        f3s, lgb + 2 * LGsz, g1, ggb + 2 * GGsz, nullptr, nullptr);

    prep_base_k<<<8, 256, 0, stream>>>(lgb + 2 * LGsz, nullptr, ggb + 2 * GGsz, nullptr,
                                       Wm + 2048, bm + 64, base);
    layer_main_t<NZ><<<gridM, blkM, 0, stream>>>(f3s, g1, nullptr, base, Wm + 2048,
        nullptr, nullptr, nullptr, nullptr,
        cur, lgb + 3 * LGsz, g3, ggb + 3 * GGsz, nullptr, nullptr);

    prep_base_k<<<8, 256, 0, stream>>>(lgb + 3 * LGsz, nullptr, ggb + 3 * GGsz, nullptr,
                                       Wm + 3072, bm + 96, base);
    layer_main_t<NZ><<<gridM, blkM, 0, stream>>>(cur, g3, nullptr, base, Wm + 3072,
        nullptr, channel, W1, b1,
        cur, lgb + 4 * LGsz, g2, ggb + 4 * GGsz, nullptr, nullptr);

    prep_base_k<<<8, 256, 0, stream>>>(lgb + 4 * LGsz, lgb, ggb + 4 * GGsz, ggb,
                                       Wm + 4096, bm + 128, base);
    layer_main_t<NZ><<<gridM, blkM, 0, stream>>>(cur, g2, g0, base, Wm + 4096,
        nullptr, nullptr, nullptr, nullptr,
        cur, lgb + 5 * LGsz, g3, ggb + 5 * GGsz, nullptr, nullptr);

    prep_base_k<<<8, 256, 0, stream>>>(lgb + 5 * LGsz, nullptr, ggb + 5 * GGsz, nullptr,
                                       Wm + 5120, bm + 160, base);
    layer_main_t<NZ><<<gridM, blkM, 0, stream>>>(cur, g3, nullptr, base, Wm + 5120,
        f3s, nullptr, nullptr, nullptr,
        cur, lgb + 6 * LGsz, g2, ggb + 6 * GGsz, W8, outp);   // fused L8 ll-dot

    layer_out_fin<NZ><<<gridO, blkO, 0, stream>>>(outp, lgb + 6 * LGsz, lgb + 2 * LGsz,
                                                  g2, g1, ggb + 6 * GGsz, ggb + 2 * GGsz,
                                                  W8, b8, out);
}

static size_t ws_req(int nz) {
    return LLsz * 2 * sizeof(unsigned short)
         + (size_t)4 * nz * GLsz * sizeof(float)
         + (7 * LGsz + 7 * GGsz + 2048 * 32 + (size_t)NB * NA) * sizeof(float);
}

extern "C" void kernel_launch(void* const* d_in, const int* in_sizes, int n_in,
                              void* d_out, int out_size, void* d_ws, size_t ws_size,
                              hipStream_t stream) {
    const float* channel = (const float*)d_in[0];
    const float* W1 = (const float*)d_in[1];
    const float* b1 = (const float*)d_in[2];
    const float* Wm = (const float*)d_in[3];
    const float* bm = (const float*)d_in[4];
    const float* W8 = (const float*)d_in[5];
    const float* b8 = (const float*)d_in[6];
    float* out = (float*)d_out;

    if (ws_size >= ws_req(2)) {
        run_pipeline<2>(channel, W1, b1, Wm, bm, W8, b8, out, out_size, d_ws, stream);
    } else {
        run_pipeline<1>(channel, W1, b1, Wm, bm, W8, b8, out, out_size, d_ws, stream);
    }
}

// Round 13
// 308.203 us; speedup vs baseline: 1.1040x; 1.1040x over previous
//
#include <hip/hip_runtime.h>

// RISnetPIv2: B=128, U=16, A=1024, FEAT=4, INFO=8.
// Round-13: best-of breeding from r11 (331.8us) + r12 (340.3us, better absmax):
//  - layer_first: REVERTED to r11's 128-thr VALU version (r12's MFMA port
//    regressed: layer_first output is antenna-major already; MFMA added
//    transpose+treesum for only 64 pk_fma saved).
//  - L7/L8 fusion KEPT from r12 (fp32 y·W8 at L7, no 33.5MB ll store/read).
//  - NEW: prep_base fused into layer_main. base[u][o] = bl[o] + lg[u]·Wlg[:,o]
//    + gg·Wgg[:,o] is per-lane scalar work: gg part once in prologue, lg part
//    per pair-iteration (16 L1 loads + 16 fma). Kills 6 dependent 8-block
//    launches (launch bubbles between every layer) + the base buffer.

#define NB 128
#define NU 16
#define NA 1024

typedef float v2f __attribute__((ext_vector_type(2)));
typedef __attribute__((ext_vector_type(8))) short bf16x8;
typedef __attribute__((ext_vector_type(16))) float f32x16;

static constexpr float PI_F = 3.14159265358979323846f;

__device__ __forceinline__ void pk_fma_acc(v2f& acc, v2f a, v2f b) {
    asm("v_pk_fma_f32 %0, %1, %2, %0" : "+v"(acc) : "v"(a), "v"(b));
}
__device__ __forceinline__ unsigned int cvtpk(float a, float b) {
    unsigned int r;
    asm("v_cvt_pk_bf16_f32 %0, %1, %2" : "=v"(r) : "v"(a), "v"(b));
    return r;  // lo = bf16(a), hi = bf16(b), RNE
}
__device__ __forceinline__ float bf16hi(float x) {   // bf16(x) as fp32
    return __uint_as_float(cvtpk(x, x) << 16);
}
__device__ __forceinline__ void unpack8(uint4 v, float x[8]) {
    x[0] = __uint_as_float(v.x << 16); x[1] = __uint_as_float(v.x & 0xffff0000u);
    x[2] = __uint_as_float(v.y << 16); x[3] = __uint_as_float(v.y & 0xffff0000u);
    x[4] = __uint_as_float(v.z << 16); x[5] = __uint_as_float(v.z & 0xffff0000u);
    x[6] = __uint_as_float(v.w << 16); x[7] = __uint_as_float(v.w & 0xffff0000u);
}
__device__ __forceinline__ void store8f(unsigned short* p, const float y[8]) {
    uint4 v;
    v.x = cvtpk(y[0], y[1]); v.y = cvtpk(y[2], y[3]);
    v.z = cvtpk(y[4], y[5]); v.w = cvtpk(y[6], y[7]);
    *reinterpret_cast<uint4*>(p) = v;
}
__device__ __forceinline__ float treesum16(f32x16 v) {
    float a0 = v[0] + v[1], a1 = v[2] + v[3], a2 = v[4] + v[5], a3 = v[6] + v[7];
    float a4 = v[8] + v[9], a5 = v[10] + v[11], a6 = v[12] + v[13], a7 = v[14] + v[15];
    float b0 = a0 + a1, b1 = a2 + a3, b2 = a4 + a5, b3 = a6 + a7;
    return (b0 + b1) + (b2 + b3);
}

// 3-level channel-merging butterfly (layer_first only, proven r7-r11)
__device__ __forceinline__ float merge3v(const v2f* y, int lane) {
    float w[4];
    const bool s0 = (lane & 1) != 0;
#pragma unroll
    for (int k = 0; k < 4; ++k) {
        float lo = s0 ? y[k].y : y[k].x;
        float hi = s0 ? y[k].x : y[k].y;
        w[k] = lo + __shfl_xor(hi, 1, 64);
    }
    const bool s1 = (lane & 2) != 0;
#pragma unroll
    for (int k = 0; k < 2; ++k) {
        float lo = s1 ? w[2 * k + 1] : w[2 * k];
        float hi = s1 ? w[2 * k] : w[2 * k + 1];
        w[k] = lo + __shfl_xor(hi, 2, 64);
    }
    const bool s2 = (lane & 4) != 0;
    float lo = s2 ? w[1] : w[0];
    float hi = s2 ? w[0] : w[1];
    return lo + __shfl_xor(hi, 4, 64);
}

// ---------------- Layer 1 (VALU; gl -> plane layout) — r11 version ----------
template <int NZ>
__global__ __launch_bounds__(128) void layer_first_t(
    const float* __restrict__ ch, const float* __restrict__ W1,
    const float* __restrict__ b1, unsigned short* __restrict__ ll_out,
    float* __restrict__ lg_out, float* __restrict__ gl_out,
    float* __restrict__ gg_out)
{
    constexpr int UN = NU / NZ;
    const int b = blockIdx.x;
    const int a = blockIdx.y * 128 + threadIdx.x;
    const int uz = blockIdx.z;
    const int lane = threadIdx.x & 63;
    const int tid = threadIdx.x;

    __shared__ float s_lg[UN][8];
    __shared__ float s_gg[8];
    for (int t = tid; t < UN * 8; t += 128) s_lg[t >> 3][t & 7] = 0.f;
    if (tid >= 64 && tid < 72) s_gg[tid & 7] = 0.f;
    __syncthreads();

    v2f glacc2[4], ggacc2[4];
#pragma unroll
    for (int i = 0; i < 4; ++i) { glacc2[i] = v2f{0.f, 0.f}; ggacc2[i] = v2f{0.f, 0.f}; }

#pragma unroll
    for (int k = 0; k < UN; ++k) {
        const int u = uz * UN + k;
        float x[4];
#pragma unroll
        for (int c = 0; c < 4; ++c)
            x[c] = ch[(((size_t)b * 4 + c) * NU + u) * NA + a];

        v2f y2[16];
        const v2f* b2 = reinterpret_cast<const v2f*>(b1);
#pragma unroll
        for (int o = 0; o < 16; ++o) y2[o] = b2[o];
#pragma unroll
        for (int c = 0; c < 4; ++c) {
            const v2f xx = v2f{x[c], x[c]};
#pragma unroll
            for (int j = 0; j < 4; ++j) {
                const v2f* wr = reinterpret_cast<const v2f*>(W1 + (j * 4 + c) * 8);
#pragma unroll
                for (int oi = 0; oi < 4; ++oi)
                    pk_fma_acc(y2[j * 4 + oi], xx, wr[oi]);
            }
        }
#pragma unroll
        for (int o = 0; o < 16; ++o)
            y2[o] = v2f{__builtin_fmaxf(y2[o].x, 0.f), __builtin_fmaxf(y2[o].y, 0.f)};

        const size_t xoff = (((size_t)(b * NU + u)) * NA + a) * 8;
        {
            uint4 v;
            v.x = cvtpk(y2[0].x, y2[0].y); v.y = cvtpk(y2[1].x, y2[1].y);
            v.z = cvtpk(y2[2].x, y2[2].y); v.w = cvtpk(y2[3].x, y2[3].y);
            *reinterpret_cast<uint4*>(ll_out + xoff) = v;
        }
#pragma unroll
        for (int i = 0; i < 4; ++i) {
            glacc2[i] += y2[8 + i];
            ggacc2[i] += y2[12 + i];
        }
        float lr = merge3v(y2 + 4, lane);
        atomicAdd(&s_lg[k][lane & 7], lr);
    }
    {   // gl partial, channel-plane layout [uz][b][c][a]
        const float invU = 1.f / 16.f;
        float ga[8];
#pragma unroll
        for (int i = 0; i < 4; ++i) { ga[2*i] = glacc2[i].x; ga[2*i+1] = glacc2[i].y; }
#pragma unroll
        for (int c = 0; c < 8; ++c)
            gl_out[(((size_t)uz * NB + b) * 8 + c) * NA + a] = ga[c] * invU;
    }
    float gga[8];
#pragma unroll
    for (int i = 0; i < 4; ++i) { gga[2*i] = ggacc2[i].x; gga[2*i+1] = ggacc2[i].y; }
    float gr = merge3v(reinterpret_cast<const v2f*>(gga), lane);
    atomicAdd(&s_gg[lane & 7], gr);
    __syncthreads();
    for (int t = tid; t < UN * 8; t += 128)
        atomicAdd(lg_out + ((size_t)b * NU + uz * UN + (t >> 3)) * 8 + (t & 7),
                  s_lg[t >> 3][t & 7]);
    if (tid >= 64 && tid < 72)
        atomicAdd(gg_out + b * 8 + (tid & 7), s_gg[tid & 7]);
}

// ---------------- Layers 2..7: MFMA, single-wave, pair-tiled ----------------
// prep_base fused: base[u][o] computed per-lane (gg part in prologue, lg part
// per pair). W8v != nullptr (layer 7): skip ll store; accumulate y·W8[0..7]
// into out_part[b,a].
template <int NZ>
__global__ __launch_bounds__(64) void layer_main_t(
    const unsigned short* ll_in, const float* __restrict__ gl_in,
    const float* __restrict__ gl_skip,
    const float* __restrict__ lg_in, const float* __restrict__ lg_skip,
    const float* __restrict__ gg_in, const float* __restrict__ gg_skip,
    const float* __restrict__ Wl, const float* __restrict__ bl,
    const unsigned short* __restrict__ ll_skip,          // layer 7: f3 ll
    const float* __restrict__ ch, const float* __restrict__ W1,
    const float* __restrict__ b1,                        // layer 5: recompute f1
    unsigned short* ll_out, float* __restrict__ lg_out,
    float* __restrict__ gl_out, float* __restrict__ gg_out,
    const float* __restrict__ W8v, float* __restrict__ out_part)
{
    constexpr int UN = NU / NZ;
    const int b = blockIdx.x;
    const int lane = threadIdx.x;       // 0..63
    const int o = lane & 31;
    const int h4 = 4 * (lane >> 5);
    const int half = lane >> 5;
    const int a32 = blockIdx.y * 32 + o;
    const int uz = blockIdx.z;
    const bool lohalf = lane < 32;
    const float invA = 1.f / 1024.f, invUA = 1.f / 16384.f;

    __shared__ float s_lg[UN][8];
    __shared__ float s_gg[8];
    __shared__ float myl[8 * 68];
    for (int t = lane; t < UN * 8; t += 64) s_lg[t >> 3][t & 7] = 0.f;
    if (lane < 8) s_gg[lane] = 0.f;
    __syncthreads();

    const int jbr = o >> 3, oi = o & 7;

    // main B fragment: k0-7 = bf16(W_ll), k8-15 = residual (lane-half split)
    bf16x8 Bfrag;
    {
        unsigned int t4[4];
#pragma unroll
        for (int r = 0; r < 4; ++r) {
            float w0 = Wl[(jbr * 32 + 2 * r) * 8 + oi];
            float w1 = Wl[(jbr * 32 + 2 * r + 1) * 8 + oi];
            float h0 = bf16hi(w0), h1 = bf16hi(w1);
            t4[r] = cvtpk(lohalf ? w0 : (w0 - h0), lohalf ? w1 : (w1 - h1));
        }
        uint4 bw = make_uint4(t4[0], t4[1], t4[2], t4[3]);
        Bfrag = __builtin_bit_cast(bf16x8, bw);
    }

    // fused prep_base: per-lane Wlg + gg-part constant
    float Wlg[8];
#pragma unroll
    for (int c = 0; c < 8; ++c) Wlg[c] = Wl[(jbr * 32 + 8 + c) * 8 + oi];
    float base_c = bl[o];
#pragma unroll
    for (int c = 0; c < 8; ++c) {
        float v = gg_in[b * 8 + c] * invUA;
        if (gg_skip) v = (v + gg_skip[b * 8 + c] * invUA) * 0.5f;
        base_c = fmaf(v, Wl[(jbr * 32 + 24 + c) * 8 + oi], base_c);
    }

    // gl gather
    float g[8];
#pragma unroll
    for (int c = 0; c < 8; ++c) {
        float s = 0.f;
#pragma unroll
        for (int z = 0; z < NZ; ++z)
            s += gl_in[(((size_t)z * NB + b) * 8 + c) * NA + a32];
        g[c] = s;
    }
    if (gl_skip) {
#pragma unroll
        for (int c = 0; c < 8; ++c) {
            float s = 0.f;
#pragma unroll
            for (int z = 0; z < NZ; ++z)
                s += gl_skip[(((size_t)z * NB + b) * 8 + c) * NA + a32];
            g[c] = (g[c] + s) * 0.5f;
        }
    }

    // cT = g·W_gl via 2 MFMAs (r11-verified)
    f32x16 cT;
    {
        bf16x8 Ag, Bh, Br;
        {
            unsigned int t4[4];
#pragma unroll
            for (int r = 0; r < 4; ++r) {
                float g0 = g[2 * r], g1 = g[2 * r + 1];
                float h0 = bf16hi(g0), h1 = bf16hi(g1);
                t4[r] = cvtpk(lohalf ? g0 : (g0 - h0), lohalf ? g1 : (g1 - h1));
            }
            uint4 u = make_uint4(t4[0], t4[1], t4[2], t4[3]);
            Ag = __builtin_bit_cast(bf16x8, u);
        }
        {
            unsigned int th[4], tr[4];
#pragma unroll
            for (int r = 0; r < 4; ++r) {
                float w0 = Wl[(jbr * 32 + 16 + 2 * r) * 8 + oi];
                float w1 = Wl[(jbr * 32 + 16 + 2 * r + 1) * 8 + oi];
                float h0 = bf16hi(w0), h1 = bf16hi(w1);
                th[r] = cvtpk(w0, w1);
                tr[r] = cvtpk(w0 - h0, w1 - h1);
            }
            uint4 uh = make_uint4(th[0], th[1], th[2], th[3]);
            uint4 ur = make_uint4(tr[0], tr[1], tr[2], tr[3]);
            Bh = __builtin_bit_cast(bf16x8, uh);
            Br = __builtin_bit_cast(bf16x8, ur);
        }
        f32x16 z16;
#pragma unroll
        for (int r = 0; r < 16; ++r) z16[r] = 0.f;
        cT = __builtin_amdgcn_mfma_f32_32x32x16_bf16(Ag, Bh, z16, 0, 0, 0);
        cT = __builtin_amdgcn_mfma_f32_32x32x16_bf16(Ag, Br, cT, 0, 0, 0);
    }

    f32x16 acc;
#pragma unroll
    for (int r = 0; r < 16; ++r) acc[r] = 0.f;
    float p8 = 0.f;

    const unsigned short* llrow =
        ll_in + (((size_t)(b * NU + uz * UN + half)) * NA + a32) * 8;
    const size_t pstride = (size_t)2 * NA * 8;
    uint4 xv = *reinterpret_cast<const uint4*>(llrow);

#pragma unroll
    for (int kp = 0; kp < UN / 2; ++kp) {
        const int u0 = uz * UN + 2 * kp;
        uint4 xnext = xv;
        if (kp + 1 < UN / 2)
            xnext = *reinterpret_cast<const uint4*>(llrow + (size_t)(kp + 1) * pstride);

        // fused base: lg part for both users
        float bse0 = base_c, bse1 = base_c;
        {
            const float* l0 = lg_in + (b * NU + u0) * 8;
            const float* l1 = l0 + 8;
            if (lg_skip) {
                const float* s0 = lg_skip + (b * NU + u0) * 8;
                const float* s1 = s0 + 8;
#pragma unroll
                for (int c = 0; c < 8; ++c) {
                    bse0 = fmaf((l0[c] * invA + s0[c] * invA) * 0.5f, Wlg[c], bse0);
                    bse1 = fmaf((l1[c] * invA + s1[c] * invA) * 0.5f, Wlg[c], bse1);
                }
            } else {
#pragma unroll
                for (int c = 0; c < 8; ++c) {
                    bse0 = fmaf(l0[c] * invA, Wlg[c], bse0);
                    bse1 = fmaf(l1[c] * invA, Wlg[c], bse1);
                }
            }
        }

        uint4 xs;
        xs.x = (unsigned)__shfl_xor((int)xv.x, 32, 64);
        xs.y = (unsigned)__shfl_xor((int)xv.y, 32, 64);
        xs.z = (unsigned)__shfl_xor((int)xv.z, 32, 64);
        xs.w = (unsigned)__shfl_xor((int)xv.w, 32, 64);
        uint4 a0u, a1u;
        a0u.x = lohalf ? xv.x : xs.x; a0u.y = lohalf ? xv.y : xs.y;
        a0u.z = lohalf ? xv.z : xs.z; a0u.w = lohalf ? xv.w : xs.w;
        a1u.x = lohalf ? xs.x : xv.x; a1u.y = lohalf ? xs.y : xv.y;
        a1u.z = lohalf ? xs.z : xv.z; a1u.w = lohalf ? xs.w : xv.w;
        bf16x8 A0 = __builtin_bit_cast(bf16x8, a0u);
        bf16x8 A1 = __builtin_bit_cast(bf16x8, a1u);

        f32x16 d0 = __builtin_amdgcn_mfma_f32_32x32x16_bf16(A0, Bfrag, cT, 0, 0, 0);
        f32x16 d1 = __builtin_amdgcn_mfma_f32_32x32x16_bf16(A1, Bfrag, cT, 0, 0, 0);
#pragma unroll
        for (int r = 0; r < 16; ++r) {
            d0[r] = __builtin_fmaxf(d0[r] + bse0, 0.f);
            d1[r] = __builtin_fmaxf(d1[r] + bse1, 0.f);
        }

        float red0 = treesum16(d0);
        red0 += __shfl_xor(red0, 32, 64);
        if (lane >= 8 && lane < 16) atomicAdd(&s_lg[2 * kp][lane - 8], red0);
        float red1 = treesum16(d1);
        red1 += __shfl_xor(red1, 32, 64);
        if (lane >= 8 && lane < 16) atomicAdd(&s_lg[2 * kp + 1][lane - 8], red1);

#pragma unroll
        for (int r = 0; r < 16; ++r) acc[r] += d0[r] + d1[r];

        if (o < 8) {
#pragma unroll
            for (int q = 0; q < 4; ++q) {
                *reinterpret_cast<float4*>(&myl[o * 68 + q * 8 + h4]) =
                    make_float4(d0[4*q], d0[4*q+1], d0[4*q+2], d0[4*q+3]);
                *reinterpret_cast<float4*>(&myl[o * 68 + 32 + q * 8 + h4]) =
                    make_float4(d1[4*q], d1[4*q+1], d1[4*q+2], d1[4*q+3]);
            }
        }
        __syncthreads();
        float y[8];
#pragma unroll
        for (int c = 0; c < 8; ++c) y[c] = myl[c * 68 + lane];

        const int u_lane = u0 + half;
        const size_t xoff = (((size_t)(b * NU + u_lane)) * NA + a32) * 8;
        if (ll_skip) {                       // layer 7: average with stored f3 ll
            float s[8];
            unpack8(*reinterpret_cast<const uint4*>(ll_skip + xoff), s);
#pragma unroll
            for (int c = 0; c < 8; ++c) y[c] = (y[c] + s[c]) * 0.5f;
        } else if (ch) {                     // layer 5: recompute f1 ll from input
            float xc[4];
#pragma unroll
            for (int c = 0; c < 4; ++c)
                xc[c] = ch[(((size_t)b * 4 + c) * NU + u_lane) * NA + a32];
            float s[8];
#pragma unroll
            for (int i = 0; i < 8; ++i) s[i] = b1[i];
#pragma unroll
            for (int c = 0; c < 4; ++c)
#pragma unroll
                for (int i = 0; i < 8; ++i)
                    s[i] = fmaf(xc[c], W1[c * 8 + i], s[i]);
#pragma unroll
            for (int i = 0; i < 8; ++i)
                y[i] = (y[i] + __builtin_fmaxf(s[i], 0.f)) * 0.5f;
        }
        if (W8v) {                           // layer 7: fused L8 ll-dot
            float d = 0.f;
#pragma unroll
            for (int c = 0; c < 8; ++c) d = fmaf(y[c], W8v[c], d);
            p8 += d;
        } else {
            store8f(ll_out + xoff, y);
        }
        __syncthreads();
        xv = xnext;
    }

    if (W8v) {
        p8 += __shfl_xor(p8, 32, 64);
        if (lohalf) atomicAdd(&out_part[(size_t)b * NA + a32], p8);
    }

    float gr = treesum16(acc);
    gr += __shfl_xor(gr, 32, 64);
    if (lane >= 24 && lane < 32) atomicAdd(&s_gg[lane - 24], gr);

    if (o >= 16 && o < 24) {
        const float invU = 1.f / 16.f;
        float* gp = gl_out + (((size_t)uz * NB + b) * 8 + (o - 16)) * NA
                  + blockIdx.y * 32;
#pragma unroll
        for (int q = 0; q < 4; ++q)
            *reinterpret_cast<float4*>(gp + q * 8 + h4) =
                make_float4(acc[4*q]*invU, acc[4*q+1]*invU, acc[4*q+2]*invU, acc[4*q+3]*invU);
    }
    __syncthreads();
    for (int t = lane; t < UN * 8; t += 64)
        atomicAdd(lg_out + ((size_t)b * NU + uz * UN + (t >> 3)) * 8 + (t & 7),
                  s_lg[t >> 3][t & 7]);
    if (lane < 8)
        atomicAdd(gg_out + b * 8 + lane, s_gg[lane]);
}

// ---------------- Layer 8 finish (r12-verified) ----------------
template <int NZ>
__global__ __launch_bounds__(128) void layer_out_fin(
    const float* __restrict__ outp,
    const float* __restrict__ lg7, const float* __restrict__ lg3,
    const float* __restrict__ gl7, const float* __restrict__ gl3,
    const float* __restrict__ gg7, const float* __restrict__ gg3,
    const float* __restrict__ W8, const float* __restrict__ b8,
    float* __restrict__ out)
{
    const int b = blockIdx.x;
    const int a = blockIdx.y * 128 + threadIdx.x;
    const float invA = 1.f / 1024.f, invUA = 1.f / 16384.f, invU = 1.f / 16.f;

    float acc = outp[(size_t)b * NA + a] * invU;

    float sb = b8[0];
#pragma unroll
    for (int c = 0; c < 8; ++c) {
        float s7 = 0.f, s3 = 0.f;
#pragma unroll
        for (int u = 0; u < NU; ++u) {
            s7 += lg7[(b * NU + u) * 8 + c];
            s3 += lg3[(b * NU + u) * 8 + c];
        }
        sb += ((s7 * invA + s3 * invA) * 0.5f * invU) * W8[8 + c];
    }
#pragma unroll
    for (int c = 0; c < 8; ++c)
        sb += ((gg7[b * 8 + c] + gg3[b * 8 + c]) * invUA * 0.5f) * W8[24 + c];

#pragma unroll
    for (int i = 0; i < 8; ++i) {
        float s7 = 0.f, s3 = 0.f;
#pragma unroll
        for (int z = 0; z < NZ; ++z) {
            s7 += gl7[(((size_t)z * NB + b) * 8 + i) * NA + a];
            s3 += gl3[(((size_t)z * NB + b) * 8 + i) * NA + a];
        }
        acc += 0.5f * (s7 + s3) * W8[16 + i];
    }
    out[(size_t)b * NA + a] = (acc + sb) * PI_F;
}

// ---------------- host ----------------
static constexpr size_t LLsz = (size_t)NB * NU * NA * 8;
static constexpr size_t GLsz = (size_t)NB * NA * 8;
static constexpr size_t LGsz = (size_t)NB * NU * 8;
static constexpr size_t GGsz = (size_t)NB * 8;

template <int NZ>
static void run_pipeline(const float* channel, const float* W1, const float* b1,
                         const float* Wm, const float* bm, const float* W8,
                         const float* b8, float* out, int out_bytes,
                         void* d_ws, hipStream_t stream)
{
    unsigned short* cur = (unsigned short*)d_ws;
    unsigned short* f3s = cur + LLsz;
    float* glb = (float*)(f3s + LLsz);
    float* g0 = glb;
    float* g1 = glb + (size_t)NZ * GLsz;
    float* g2 = glb + (size_t)2 * NZ * GLsz;
    float* g3 = glb + (size_t)3 * NZ * GLsz;
    float* lgb = glb + (size_t)4 * NZ * GLsz;
    float* ggb = lgb + 7 * LGsz;
    float* outp = ggb + 7 * GGsz;                   // [B,A] fused L8 partial

    // one contiguous zero: lg sums + gg sums + outp
    hipMemsetAsync(lgb, 0,
                   (7 * LGsz + 7 * GGsz + (size_t)NB * NA) * sizeof(float), stream);

    dim3 gridF(NB, NA / 128, NZ), blkF(128);
    dim3 gridM(NB, NA / 32, NZ), blkM(64);
    dim3 gridO(NB, NA / 128), blkO(128);

    // L1
    layer_first_t<NZ><<<gridF, blkF, 0, stream>>>(channel, W1, b1, cur, lgb, g0, ggb);

    // L2: cur -> cur, g0 -> g2
    layer_main_t<NZ><<<gridM, blkM, 0, stream>>>(cur, g0, nullptr,
        lgb, nullptr, ggb, nullptr, Wm, bm,
        nullptr, nullptr, nullptr, nullptr,
        cur, lgb + 1 * LGsz, g2, ggb + 1 * GGsz, nullptr, nullptr);

    // L3: cur -> f3s, g2 -> g1
    layer_main_t<NZ><<<gridM, blkM, 0, stream>>>(cur, g2, nullptr,
        lgb + 1 * LGsz, nullptr, ggb + 1 * GGsz, nullptr, Wm + 1024, bm + 32,
        nullptr, nullptr, nullptr, nullptr,
        f3s, lgb + 2 * LGsz, g1, ggb + 2 * GGsz, nullptr, nullptr);

    // L4: f3s -> cur, g1 -> g3
    layer_main_t<NZ><<<gridM, blkM, 0, stream>>>(f3s, g1, nullptr,
        lgb + 2 * LGsz, nullptr, ggb + 2 * GGsz, nullptr, Wm + 2048, bm + 64,
        nullptr, nullptr, nullptr, nullptr,
        cur, lgb + 3 * LGsz, g3, ggb + 3 * GGsz, nullptr, nullptr);

    // L5: cur -> cur, g3 -> g2; ll-skip = recomputed f1
    layer_main_t<NZ><<<gridM, blkM, 0, stream>>>(cur, g3, nullptr,
        lgb + 3 * LGsz, nullptr, ggb + 3 * GGsz, nullptr, Wm + 3072, bm + 96,
        nullptr, channel, W1, b1,
        cur, lgb + 4 * LGsz, g2, ggb + 4 * GGsz, nullptr, nullptr);

    // L6: cur -> cur, g2 -> g3; input-side skip with f1 factors
    layer_main_t<NZ><<<gridM, blkM, 0, stream>>>(cur, g2, g0,
        lgb + 4 * LGsz, lgb, ggb + 4 * GGsz, ggb, Wm + 4096, bm + 128,
        nullptr, nullptr, nullptr, nullptr,
        cur, lgb + 5 * LGsz, g3, ggb + 5 * GGsz, nullptr, nullptr);

    // L7: cur -> (fused L8 dot), g3 -> g2; ll-skip = f3s
    layer_main_t<NZ><<<gridM, blkM, 0, stream>>>(cur, g3, nullptr,
        lgb + 5 * LGsz, nullptr, ggb + 5 * GGsz, nullptr, Wm + 5120, bm + 160,
        f3s, nullptr, nullptr, nullptr,
        cur, lgb + 6 * LGsz, g2, ggb + 6 * GGsz, W8, outp);

    // L8 finish
    layer_out_fin<NZ><<<gridO, blkO, 0, stream>>>(outp, lgb + 6 * LGsz, lgb + 2 * LGsz,
                                                  g2, g1, ggb + 6 * GGsz, ggb + 2 * GGsz,
                                                  W8, b8, out);
}

static size_t ws_req(int nz) {
    return LLsz * 2 * sizeof(unsigned short)
         + (size_t)4 * nz * GLsz * sizeof(float)
         + (7 * LGsz + 7 * GGsz + (size_t)NB * NA) * sizeof(float);
}

extern "C" void kernel_launch(void* const* d_in, const int* in_sizes, int n_in,
                              void* d_out, int out_size, void* d_ws, size_t ws_size,
                              hipStream_t stream) {
    const float* channel = (const float*)d_in[0];
    const float* W1 = (const float*)d_in[1];
    const float* b1 = (const float*)d_in[2];
    const float* Wm = (const float*)d_in[3];
    const float* bm = (const float*)d_in[4];
    const float* W8 = (const float*)d_in[5];
    const float* b8 = (const float*)d_in[6];
    float* out = (float*)d_out;

    if (ws_size >= ws_req(2)) {
        run_pipeline<2>(channel, W1, b1, Wm, bm, W8, b8, out, out_size, d_ws, stream);
    } else {
        run_pipeline<1>(channel, W1, b1, Wm, bm, W8, b8, out, out_size, d_ws, stream);
    }
}